// Round 4
// baseline (363.365 us; speedup 1.0000x reference)
//
#include <hip/hip_runtime.h>
#include <math.h>

#define HH 384
#define WW 384
#define NG 16
#define HW (HH*WW)

// fused tiles: 64 wide x 16 tall, 256 threads = (16 xg, 16 y), 4 px/thread
#define FTW 64
#define FTH 16

// ---------------------------------------------------------------------------
// Layer 1: x = data - 3.5 ; h = relu(gconv(x, w1*maskA, b1))
// maskA taps: rows 0,1 all 5 cols; row 2 cols 0,1
// Weights read directly from global with block-uniform addresses -> s_load.
// ---------------------------------------------------------------------------
__global__ __launch_bounds__(256) void conv1_kernel(
    const int* __restrict__ data, const float* __restrict__ w1,
    const float* __restrict__ b1, float* __restrict__ h)
{
    const int g  = blockIdx.z;
    const int x0 = blockIdx.x * 64, y0 = blockIdx.y * 4;
    __shared__ float s_in[4 + 2][64 + 4];
    const int tid = threadIdx.y * 64 + threadIdx.x;

    const float* wg = w1 + (size_t)g * 3 * 25;   // [oc][25]
    const float* bg = b1 + (size_t)g * 3;

    const int* plane = data + g * HW;
    for (int i = tid; i < 6 * 68; i += 256) {
        int rr = i / 68, cc = i % 68;
        int gy = y0 + rr - 2, gx = x0 + cc - 2;
        float v = 0.f;
        if (gy >= 0 && gx >= 0 && gx < WW)
            v = (float)plane[gy * WW + gx] - 3.5f;
        s_in[rr][cc] = v;
    }
    __syncthreads();

    const int tx = threadIdx.x, ty = threadIdx.y;
    float a0 = bg[0], a1 = bg[1], a2 = bg[2];
#pragma unroll
    for (int r = 0; r < 3; ++r) {
        const int cmax = (r < 2) ? 5 : 2;
#pragma unroll
        for (int c = 0; c < 5; ++c) {
            if (c >= cmax) break;
            float v = s_in[ty + r][tx + c];
            a0 += v * wg[0 * 25 + r * 5 + c];
            a1 += v * wg[1 * 25 + r * 5 + c];
            a2 += v * wg[2 * 25 + r * 5 + c];
        }
    }
    const int y = y0 + ty, x = x0 + tx;
    int o = (g * 3) * HW + y * WW + x;
    h[o]          = fmaxf(a0, 0.f);
    h[o + HW]     = fmaxf(a1, 0.f);
    h[o + 2 * HW] = fmaxf(a2, 0.f);
}

// ---------------------------------------------------------------------------
// Fused residual block: out = in + relu(convB(relu(convB(in, wa)), wb))
// Tile FTHxFTW. IN origin (y0-4, x0-4), dims (FTH+4)x(FTW+8).
// T (intermediate) origin (y0-2, x0-2), dims (FTH+2)x(FTW+4).
// maskB taps: rows 0,1 all 5 cols; row 2 cols 0..2.
// Weights/biases: uniform global reads (scalar pipe), NOT LDS.
// ---------------------------------------------------------------------------
__global__ __launch_bounds__(256) void res_block_kernel(
    const float* __restrict__ in, const float* __restrict__ wa,
    const float* __restrict__ ba, const float* __restrict__ wb,
    const float* __restrict__ bb, float* __restrict__ out)
{
    const int g  = blockIdx.z;
    const int x0 = blockIdx.x * FTW, y0 = blockIdx.y * FTH;
    __shared__ __align__(16) float IN[3][FTH + 4][FTW + 8];
    __shared__ __align__(16) float T [3][FTH + 2][FTW + 4];
    const int tid = threadIdx.y * 16 + threadIdx.x;

    const float* wga = wa + (size_t)g * 9 * 25;  // [oc][ic][25]
    const float* bga = ba + (size_t)g * 3;
    const float* wgb = wb + (size_t)g * 9 * 25;
    const float* bgb = bb + (size_t)g * 3;

    // ---- stage input tile (zero-padded), float4 fast path ----
    const float* base = in + (size_t)g * 3 * HW;
    for (int i = tid; i < 3 * (FTH + 4) * ((FTW + 8) / 4); i += 256) { // 1080
        int ch = i / 360, rem = i % 360, rr = rem / 18, q = rem % 18;
        int gy = y0 - 4 + rr, gx0 = x0 - 4 + 4 * q;
        float4 v = make_float4(0.f, 0.f, 0.f, 0.f);
        if (gy >= 0) {
            const float* rowp = base + (size_t)ch * HW + (size_t)gy * WW;
            if (gx0 >= 0 && gx0 + 3 < WW) {
                v = *(const float4*)(rowp + gx0);
            } else {
                float t[4];
#pragma unroll
                for (int p = 0; p < 4; ++p) {
                    int gx = gx0 + p;
                    t[p] = (gx >= 0 && gx < WW) ? rowp[gx] : 0.f;
                }
                v = make_float4(t[0], t[1], t[2], t[3]);
            }
        }
        *(float4*)&IN[ch][rr][4 * q] = v;
    }
    __syncthreads();

    // ---- first conv: T = relu(convB(IN)), on (FTH+2)x(FTW+4) region ----
    for (int i = tid; i < (FTH + 2) * ((FTW + 4) / 4); i += 256) {  // 306
        int ty = i / 17, q = i % 17, tx0 = 4 * q;
        int gty = y0 - 2 + ty, gtx0 = x0 - 2 + tx0;
        float a0[4], a1[4], a2[4];
#pragma unroll
        for (int p = 0; p < 4; ++p) { a0[p] = bga[0]; a1[p] = bga[1]; a2[p] = bga[2]; }
#pragma unroll
        for (int ic = 0; ic < 3; ++ic) {
#pragma unroll
            for (int r = 0; r < 3; ++r) {
                float4 u0 = *(const float4*)&IN[ic][ty + r][tx0];
                float4 u1 = *(const float4*)&IN[ic][ty + r][tx0 + 4];
                float v[8] = {u0.x, u0.y, u0.z, u0.w, u1.x, u1.y, u1.z, u1.w};
                const int cmax = (r < 2) ? 5 : 3;
#pragma unroll
                for (int c = 0; c < 5; ++c) {
                    if (c >= cmax) break;
                    float w0 = wga[(0 * 3 + ic) * 25 + r * 5 + c];
                    float w1 = wga[(1 * 3 + ic) * 25 + r * 5 + c];
                    float w2 = wga[(2 * 3 + ic) * 25 + r * 5 + c];
#pragma unroll
                    for (int p = 0; p < 4; ++p) {
                        a0[p] += w0 * v[c + p];
                        a1[p] += w1 * v[c + p];
                        a2[p] += w2 * v[c + p];
                    }
                }
            }
        }
        float r0[4], r1[4], r2[4];
#pragma unroll
        for (int p = 0; p < 4; ++p) {
            int gx = gtx0 + p;
            bool ok = (gty >= 0) && (gx >= 0) && (gx < WW);
            r0[p] = ok ? fmaxf(a0[p], 0.f) : 0.f;
            r1[p] = ok ? fmaxf(a1[p], 0.f) : 0.f;
            r2[p] = ok ? fmaxf(a2[p], 0.f) : 0.f;
        }
        *(float4*)&T[0][ty][tx0] = make_float4(r0[0], r0[1], r0[2], r0[3]);
        *(float4*)&T[1][ty][tx0] = make_float4(r1[0], r1[1], r1[2], r1[3]);
        *(float4*)&T[2][ty][tx0] = make_float4(r2[0], r2[1], r2[2], r2[3]);
    }
    __syncthreads();

    // ---- second conv + residual add + write ----
    const int xg = threadIdx.x, yy = threadIdx.y;
    float a0[4], a1[4], a2[4];
#pragma unroll
    for (int p = 0; p < 4; ++p) { a0[p] = bgb[0]; a1[p] = bgb[1]; a2[p] = bgb[2]; }
#pragma unroll
    for (int ic = 0; ic < 3; ++ic) {
#pragma unroll
        for (int r = 0; r < 3; ++r) {
            float4 u0 = *(const float4*)&T[ic][yy + r][4 * xg];
            float4 u1 = *(const float4*)&T[ic][yy + r][4 * xg + 4];
            float v[8] = {u0.x, u0.y, u0.z, u0.w, u1.x, u1.y, u1.z, u1.w};
            const int cmax = (r < 2) ? 5 : 3;
#pragma unroll
            for (int c = 0; c < 5; ++c) {
                if (c >= cmax) break;
                float w0 = wgb[(0 * 3 + ic) * 25 + r * 5 + c];
                float w1 = wgb[(1 * 3 + ic) * 25 + r * 5 + c];
                float w2 = wgb[(2 * 3 + ic) * 25 + r * 5 + c];
#pragma unroll
                for (int p = 0; p < 4; ++p) {
                    a0[p] += w0 * v[c + p];
                    a1[p] += w1 * v[c + p];
                    a2[p] += w2 * v[c + p];
                }
            }
        }
    }
    const int gy = y0 + yy;
    float* ob = out + (size_t)g * 3 * HW + (size_t)gy * WW + x0 + 4 * xg;
    float4 h0 = *(const float4*)&IN[0][yy + 4][4 * xg + 4];
    float4 h1 = *(const float4*)&IN[1][yy + 4][4 * xg + 4];
    float4 h2 = *(const float4*)&IN[2][yy + 4][4 * xg + 4];
    *(float4*)(ob)          = make_float4(h0.x + fmaxf(a0[0],0.f), h0.y + fmaxf(a0[1],0.f),
                                          h0.z + fmaxf(a0[2],0.f), h0.w + fmaxf(a0[3],0.f));
    *(float4*)(ob + HW)     = make_float4(h1.x + fmaxf(a1[0],0.f), h1.y + fmaxf(a1[1],0.f),
                                          h1.z + fmaxf(a1[2],0.f), h1.w + fmaxf(a1[3],0.f));
    *(float4*)(ob + 2*HW)   = make_float4(h2.x + fmaxf(a2[0],0.f), h2.y + fmaxf(a2[1],0.f),
                                          h2.z + fmaxf(a2[2],0.f), h2.w + fmaxf(a2[3],0.f));
}

// ---------------------------------------------------------------------------
// Fast branchless transcendentals
// ---------------------------------------------------------------------------
__device__ __forceinline__ float fast_rcp(float x) {
    return __builtin_amdgcn_rcpf(x);
}

// Winitzki erf approximation, max abs err ~1.3e-4
__device__ __forceinline__ float fast_erf(float x) {
    const float a = 0.147f;
    const float c = 1.27323954f;  // 4/pi
    float x2 = x * x;
    float ax2 = a * x2;
    float t = x2 * (c + ax2) * fast_rcp(1.f + ax2);
    float e = __expf(-t);
    float s = __builtin_amdgcn_sqrtf(fmaxf(1.f - e, 0.f));
    return copysignf(s, x);
}

__device__ __forceinline__ float fast_softplus(float x) {
    float t = __expf(-fabsf(x));
    return fmaxf(x, 0.f) + __logf(1.f + t);
}

// ---------------------------------------------------------------------------
// Final conv (9 out ch per group) fused with mixture-CDF -> pmf * 65536
// 4 px per thread. IN origin (y0-2, x0-4), dims (FTH+2)x(FTW+8).
// Weights/biases: uniform global reads (scalar pipe), NOT LDS.
// ---------------------------------------------------------------------------
__global__ __launch_bounds__(256) void final_kernel(
    const float* __restrict__ hbuf, const float* __restrict__ wf,
    const float* __restrict__ bf, float* __restrict__ out)
{
    const int g  = blockIdx.z;
    const int x0 = blockIdx.x * FTW, y0 = blockIdx.y * FTH;
    __shared__ __align__(16) float IN[3][FTH + 2][FTW + 8];
    const int tid = threadIdx.y * 16 + threadIdx.x;

    const float* wg = wf + (size_t)g * 9 * 3 * 25;  // [m][ic][25]
    const float* bg = bf + (size_t)g * 9;

    const float* base = hbuf + (size_t)g * 3 * HW;
    for (int i = tid; i < 3 * (FTH + 2) * ((FTW + 8) / 4); i += 256) { // 972
        int ch = i / 324, rem = i % 324, rr = rem / 18, q = rem % 18;
        int gy = y0 - 2 + rr, gx0 = x0 - 4 + 4 * q;
        float4 v = make_float4(0.f, 0.f, 0.f, 0.f);
        if (gy >= 0) {
            const float* rowp = base + (size_t)ch * HW + (size_t)gy * WW;
            if (gx0 >= 0 && gx0 + 3 < WW) {
                v = *(const float4*)(rowp + gx0);
            } else {
                float t[4];
#pragma unroll
                for (int p = 0; p < 4; ++p) {
                    int gx = gx0 + p;
                    t[p] = (gx >= 0 && gx < WW) ? rowp[gx] : 0.f;
                }
                v = make_float4(t[0], t[1], t[2], t[3]);
            }
        }
        *(float4*)&IN[ch][rr][4 * q] = v;
    }
    __syncthreads();

    const int xg = threadIdx.x, yy = threadIdx.y;
    float acc[9][4];
#pragma unroll
    for (int m = 0; m < 9; ++m)
#pragma unroll
        for (int p = 0; p < 4; ++p) acc[m][p] = bg[m];

#pragma unroll
    for (int ic = 0; ic < 3; ++ic) {
#pragma unroll
        for (int r = 0; r < 3; ++r) {
            float4 u0 = *(const float4*)&IN[ic][yy + r][4 * xg];
            float4 u1 = *(const float4*)&IN[ic][yy + r][4 * xg + 4];
            float4 u2 = *(const float4*)&IN[ic][yy + r][4 * xg + 8];
            float v[12] = {u0.x, u0.y, u0.z, u0.w, u1.x, u1.y, u1.z, u1.w,
                           u2.x, u2.y, u2.z, u2.w};
            const int cmax = (r < 2) ? 5 : 3;
#pragma unroll
            for (int c = 0; c < 5; ++c) {
                if (c >= cmax) break;
#pragma unroll
                for (int m = 0; m < 9; ++m) {
                    float w = wg[(m * 3 + ic) * 25 + r * 5 + c];
#pragma unroll
                    for (int p = 0; p < 4; ++p)
                        acc[m][p] += w * v[c + p + 2];   // IN origin x0-4
                }
            }
        }
    }

    // ---- mixture per pixel ----
    const float inv_sqrt2 = 0.70710678118654752440f;
    float wm0[4], wm1[4], wm2[4], mu0[4], mu1[4], mu2[4], k0[4], k1[4], k2[4];
#pragma unroll
    for (int p = 0; p < 4; ++p) {
        float lw0 = acc[0][p], m0 = acc[1][p], ls0 = acc[2][p];
        float lw1 = acc[3][p], m1 = acc[4][p], ls1 = acc[5][p];
        float lw2 = acc[6][p], m2 = acc[7][p], ls2 = acc[8][p];
        float lmax = fmaxf(lw0, fmaxf(lw1, lw2));
        float e0 = __expf(lw0 - lmax), e1 = __expf(lw1 - lmax), e2 = __expf(lw2 - lmax);
        float inv_sum = fast_rcp(e0 + e1 + e2);
        wm0[p] = 0.5f * e0 * inv_sum;
        wm1[p] = 0.5f * e1 * inv_sum;
        wm2[p] = 0.5f * e2 * inv_sum;
        mu0[p] = m0; mu1[p] = m1; mu2[p] = m2;
        k0[p] = inv_sqrt2 * fast_rcp(fast_softplus(ls0) + 1e-6f);
        k1[p] = inv_sqrt2 * fast_rcp(fast_softplus(ls1) + 1e-6f);
        k2[p] = inv_sqrt2 * fast_rcp(fast_softplus(ls2) + 1e-6f);
    }

    const int gy = y0 + yy;
    float* ob = out + ((size_t)g * 8 * HH + gy) * WW + x0 + 4 * xg;
    float prev[4] = {0.f, 0.f, 0.f, 0.f};
#pragma unroll
    for (int j = 0; j <= 8; ++j) {
        float edge = (float)j - 4.0f;
        float cdf[4];
#pragma unroll
        for (int p = 0; p < 4; ++p) {
            cdf[p] = wm0[p] * (1.f + fast_erf((edge - mu0[p]) * k0[p]))
                   + wm1[p] * (1.f + fast_erf((edge - mu1[p]) * k1[p]))
                   + wm2[p] * (1.f + fast_erf((edge - mu2[p]) * k2[p]));
        }
        if (j > 0) {
            *(float4*)(ob + (size_t)(j - 1) * HW) =
                make_float4((cdf[0] - prev[0]) * 65536.f, (cdf[1] - prev[1]) * 65536.f,
                            (cdf[2] - prev[2]) * 65536.f, (cdf[3] - prev[3]) * 65536.f);
        }
#pragma unroll
        for (int p = 0; p < 4; ++p) prev[p] = cdf[p];
    }
}

// ---------------------------------------------------------------------------
extern "C" void kernel_launch(void* const* d_in, const int* in_sizes, int n_in,
                              void* d_out, int out_size, void* d_ws, size_t ws_size,
                              hipStream_t stream)
{
    const int*   data = (const int*)d_in[0];
    const float* w1   = (const float*)d_in[1];
    const float* b1   = (const float*)d_in[2];
    const float* rw   = (const float*)d_in[3];
    const float* rb   = (const float*)d_in[4];
    const float* wf   = (const float*)d_in[5];
    const float* bf   = (const float*)d_in[6];
    float* out = (float*)d_out;

    float* A = (float*)d_ws;
    float* B = A + (size_t)48 * HW;

    conv1_kernel<<<dim3(6, 96, 16), dim3(64, 4), 0, stream>>>(data, w1, b1, A);

    dim3 blk(16, 16, 1);
    dim3 grd(WW / FTW, HH / FTH, NG);
    const float* cur = A;
    float* nxt = B;
    for (int i = 0; i < 5; ++i) {
        const float* wa = rw + (size_t)(i * 2 + 0) * 48 * 3 * 25;
        const float* ba = rb + (i * 2 + 0) * 48;
        const float* wb = rw + (size_t)(i * 2 + 1) * 48 * 3 * 25;
        const float* bb = rb + (i * 2 + 1) * 48;
        res_block_kernel<<<grd, blk, 0, stream>>>(cur, wa, ba, wb, bb, nxt);
        const float* t = cur; cur = nxt; nxt = (float*)t;
    }
    final_kernel<<<grd, blk, 0, stream>>>(cur, wf, bf, out);
}

// Round 6
// 334.016 us; speedup vs baseline: 1.0879x; 1.0879x over previous
//
#include <hip/hip_runtime.h>
#include <math.h>

#define HH 384
#define WW 384
#define NG 16
#define HW (HH*WW)

// fused tiles: 64 wide x 16 tall, 256 threads = (16 xg, 16 y), 4 px/thread
#define FTW 64
#define FTH 16

// ---------------------------------------------------------------------------
// Generic 13-tap (maskB) accumulate: a[oc][p] += W[oc][r*5+c] * row[c+p]
// P points at [row0][col0] of the input window; PITCH = row stride in floats.
// taps: r=0,1 -> c=0..4 ; r=2 -> c=0..2 (linear index r*5+c in 0..12)
// ---------------------------------------------------------------------------
template <int PITCH>
__device__ __forceinline__ void accum13(const float* __restrict__ P,
                                        int ty, int tx0,
                                        float (&a)[3][4],
                                        const float (&Wl)[3][13])
{
#pragma unroll
    for (int r = 0; r < 3; ++r) {
        const float* row = P + (ty + r) * PITCH + tx0;
        float4 u0 = *(const float4*)(row);
        float4 u1 = *(const float4*)(row + 4);
        float v[8] = {u0.x, u0.y, u0.z, u0.w, u1.x, u1.y, u1.z, u1.w};
        const int cmax = (r < 2) ? 5 : 3;
#pragma unroll
        for (int c = 0; c < 5; ++c) {
            if (c >= cmax) break;
#pragma unroll
            for (int oc = 0; oc < 3; ++oc) {
                float w = Wl[oc][r * 5 + c];
#pragma unroll
                for (int p = 0; p < 4; ++p)
                    a[oc][p] += w * v[c + p];
            }
        }
    }
}

// ---------------------------------------------------------------------------
// Layer 1: x = data - 3.5 ; h = relu(gconv(x, w1*maskA, b1))
// maskA taps: rows 0,1 all 5 cols; row 2 cols 0,1 (12 taps, linear 0..11).
// Tile 64x16, 4 px/thread. Weights in registers.
// ---------------------------------------------------------------------------
__global__ __launch_bounds__(256) void conv1_kernel(
    const int* __restrict__ data, const float* __restrict__ w1,
    const float* __restrict__ b1, float* __restrict__ h)
{
    const int g  = blockIdx.z;
    const int x0 = blockIdx.x * FTW, y0 = blockIdx.y * FTH;
    __shared__ __align__(16) float s_in[FTH + 2][FTW + 8];
    const int tid = threadIdx.y * 16 + threadIdx.x;

    const float* wg = w1 + (size_t)g * 3 * 25;
    const float* bg = b1 + (size_t)g * 3;
    float W[3][12];
#pragma unroll
    for (int oc = 0; oc < 3; ++oc)
#pragma unroll
        for (int t = 0; t < 12; ++t)
            W[oc][t] = wg[oc * 25 + t];
    float B[3] = {bg[0], bg[1], bg[2]};

    // stage 18 rows x 72 cols (origin y0-2, x0-4), int -> float - 3.5
    const int* plane = data + g * HW;
    for (int i = tid; i < 18 * 18; i += 256) {
        int rr = i / 18, q = i % 18;
        int gy = y0 - 2 + rr, gx0 = x0 - 4 + 4 * q;
        float4 v = make_float4(0.f, 0.f, 0.f, 0.f);
        if (gy >= 0) {
            const int* rowp = plane + gy * WW;
            if (gx0 >= 0 && gx0 + 3 < WW) {
                int4 iv = *(const int4*)(rowp + gx0);
                v = make_float4((float)iv.x - 3.5f, (float)iv.y - 3.5f,
                                (float)iv.z - 3.5f, (float)iv.w - 3.5f);
            } else {
                float t[4];
#pragma unroll
                for (int p = 0; p < 4; ++p) {
                    int gx = gx0 + p;
                    t[p] = (gx >= 0 && gx < WW) ? (float)rowp[gx] - 3.5f : 0.f;
                }
                v = make_float4(t[0], t[1], t[2], t[3]);
            }
        }
        *(float4*)&s_in[rr][4 * q] = v;
    }
    __syncthreads();

    const int xg = threadIdx.x, yy = threadIdx.y;
    float a[3][4];
#pragma unroll
    for (int oc = 0; oc < 3; ++oc)
#pragma unroll
        for (int p = 0; p < 4; ++p) a[oc][p] = B[oc];

#pragma unroll
    for (int r = 0; r < 3; ++r) {
        const float* row = &s_in[yy + r][4 * xg];
        float4 u0 = *(const float4*)(row);
        float4 u1 = *(const float4*)(row + 4);
        float4 u2 = *(const float4*)(row + 8);
        float v[12] = {u0.x, u0.y, u0.z, u0.w, u1.x, u1.y, u1.z, u1.w,
                       u2.x, u2.y, u2.z, u2.w};
        const int cmax = (r < 2) ? 5 : 2;      // maskA
#pragma unroll
        for (int c = 0; c < 5; ++c) {
            if (c >= cmax) break;
#pragma unroll
            for (int oc = 0; oc < 3; ++oc) {
                float w = W[oc][r * 5 + c];
#pragma unroll
                for (int p = 0; p < 4; ++p)
                    a[oc][p] += w * v[c + p + 2];   // input origin x0-4
            }
        }
    }
    const int gy = y0 + yy;
    float* ob = h + (size_t)g * 3 * HW + (size_t)gy * WW + x0 + 4 * xg;
#pragma unroll
    for (int oc = 0; oc < 3; ++oc) {
        *(float4*)(ob + (size_t)oc * HW) =
            make_float4(fmaxf(a[oc][0], 0.f), fmaxf(a[oc][1], 0.f),
                        fmaxf(a[oc][2], 0.f), fmaxf(a[oc][3], 0.f));
    }
}

// ---------------------------------------------------------------------------
// Fused residual block: out = in + relu(convB(relu(convB(in, wa)), wb))
// IN origin (y0-4, x0-4): [3][20][72]; T origin (y0-2, x0-2): [3][18][68].
// Weights loaded per-ic into registers, reused across this thread's items.
// ---------------------------------------------------------------------------
__global__ __launch_bounds__(256) void res_block_kernel(
    const float* __restrict__ in, const float* __restrict__ wa,
    const float* __restrict__ ba, const float* __restrict__ wb,
    const float* __restrict__ bb, float* __restrict__ out)
{
    const int g  = blockIdx.z;
    const int x0 = blockIdx.x * FTW, y0 = blockIdx.y * FTH;
    __shared__ __align__(16) float IN[3][FTH + 4][FTW + 8];
    __shared__ __align__(16) float T [3][FTH + 2][FTW + 4];
    const int tid = threadIdx.y * 16 + threadIdx.x;

    const float* wga = wa + (size_t)g * 9 * 25;
    const float* bga = ba + (size_t)g * 3;
    const float* wgb = wb + (size_t)g * 9 * 25;
    const float* bgb = bb + (size_t)g * 3;
    float Ba[3] = {bga[0], bga[1], bga[2]};
    float Bb[3] = {bgb[0], bgb[1], bgb[2]};

    // ---- stage input tile (zero-padded), float4 fast path ----
    const float* base = in + (size_t)g * 3 * HW;
    for (int i = tid; i < 3 * (FTH + 4) * ((FTW + 8) / 4); i += 256) { // 1080
        int ch = i / 360, rem = i % 360, rr = rem / 18, q = rem % 18;
        int gy = y0 - 4 + rr, gx0 = x0 - 4 + 4 * q;
        float4 v = make_float4(0.f, 0.f, 0.f, 0.f);
        if (gy >= 0) {
            const float* rowp = base + (size_t)ch * HW + (size_t)gy * WW;
            if (gx0 >= 0 && gx0 + 3 < WW) {
                v = *(const float4*)(rowp + gx0);
            } else {
                float t[4];
#pragma unroll
                for (int p = 0; p < 4; ++p) {
                    int gx = gx0 + p;
                    t[p] = (gx >= 0 && gx < WW) ? rowp[gx] : 0.f;
                }
                v = make_float4(t[0], t[1], t[2], t[3]);
            }
        }
        *(float4*)&IN[ch][rr][4 * q] = v;
    }
    __syncthreads();

    // ---- first conv: T = relu(convB(IN)) over 18x68 region (306 items) ----
    {
        const int i0 = tid, i1 = tid + 256;
        const bool has1 = (i1 < 306);
        const int ty0 = i0 / 17, tx00 = 4 * (i0 % 17);
        const int ty1 = i1 / 17, tx01 = 4 * (i1 % 17);
        float a0[3][4], a1[3][4];
#pragma unroll
        for (int oc = 0; oc < 3; ++oc)
#pragma unroll
            for (int p = 0; p < 4; ++p) { a0[oc][p] = Ba[oc]; a1[oc][p] = Ba[oc]; }

#pragma unroll
        for (int ic = 0; ic < 3; ++ic) {
            float Wl[3][13];
#pragma unroll
            for (int oc = 0; oc < 3; ++oc)
#pragma unroll
                for (int t = 0; t < 13; ++t)
                    Wl[oc][t] = wga[(oc * 3 + ic) * 25 + t];
            accum13<FTW + 8>(&IN[ic][0][0], ty0, tx00, a0, Wl);
            if (has1)
                accum13<FTW + 8>(&IN[ic][0][0], ty1, tx01, a1, Wl);
        }

        // mask + write item 0
        {
            int gty = y0 - 2 + ty0, gtx0 = x0 - 2 + tx00;
#pragma unroll
            for (int oc = 0; oc < 3; ++oc) {
                float r_[4];
#pragma unroll
                for (int p = 0; p < 4; ++p) {
                    int gx = gtx0 + p;
                    bool ok = (gty >= 0) && (gx >= 0) && (gx < WW);
                    r_[p] = ok ? fmaxf(a0[oc][p], 0.f) : 0.f;
                }
                *(float4*)&T[oc][ty0][tx00] = make_float4(r_[0], r_[1], r_[2], r_[3]);
            }
        }
        if (has1) {
            int gty = y0 - 2 + ty1, gtx0 = x0 - 2 + tx01;
#pragma unroll
            for (int oc = 0; oc < 3; ++oc) {
                float r_[4];
#pragma unroll
                for (int p = 0; p < 4; ++p) {
                    int gx = gtx0 + p;
                    bool ok = (gty >= 0) && (gx >= 0) && (gx < WW);
                    r_[p] = ok ? fmaxf(a1[oc][p], 0.f) : 0.f;
                }
                *(float4*)&T[oc][ty1][tx01] = make_float4(r_[0], r_[1], r_[2], r_[3]);
            }
        }
    }
    __syncthreads();

    // ---- second conv + residual add + write ----
    const int xg = threadIdx.x, yy = threadIdx.y;
    float a[3][4];
#pragma unroll
    for (int oc = 0; oc < 3; ++oc)
#pragma unroll
        for (int p = 0; p < 4; ++p) a[oc][p] = Bb[oc];

#pragma unroll
    for (int ic = 0; ic < 3; ++ic) {
        float Wl[3][13];
#pragma unroll
        for (int oc = 0; oc < 3; ++oc)
#pragma unroll
            for (int t = 0; t < 13; ++t)
                Wl[oc][t] = wgb[(oc * 3 + ic) * 25 + t];
        accum13<FTW + 4>(&T[ic][0][0], yy, 4 * xg, a, Wl);
    }

    const int gy = y0 + yy;
    float* ob = out + (size_t)g * 3 * HW + (size_t)gy * WW + x0 + 4 * xg;
#pragma unroll
    for (int oc = 0; oc < 3; ++oc) {
        float4 h0 = *(const float4*)&IN[oc][yy + 4][4 * xg + 4];
        *(float4*)(ob + (size_t)oc * HW) =
            make_float4(h0.x + fmaxf(a[oc][0], 0.f), h0.y + fmaxf(a[oc][1], 0.f),
                        h0.z + fmaxf(a[oc][2], 0.f), h0.w + fmaxf(a[oc][3], 0.f));
    }
}

// ---------------------------------------------------------------------------
// Fast branchless transcendentals
// ---------------------------------------------------------------------------
__device__ __forceinline__ float fast_rcp(float x) {
    return __builtin_amdgcn_rcpf(x);
}

// Winitzki erf approximation, max abs err ~1.3e-4
__device__ __forceinline__ float fast_erf(float x) {
    const float a = 0.147f;
    const float c = 1.27323954f;  // 4/pi
    float x2 = x * x;
    float ax2 = a * x2;
    float t = x2 * (c + ax2) * fast_rcp(1.f + ax2);
    float e = __expf(-t);
    float s = __builtin_amdgcn_sqrtf(fmaxf(1.f - e, 0.f));
    return copysignf(s, x);
}

__device__ __forceinline__ float fast_softplus(float x) {
    float t = __expf(-fabsf(x));
    return fmaxf(x, 0.f) + __logf(1.f + t);
}

// ---------------------------------------------------------------------------
// Final conv (9 out ch per group) fused with mixture-CDF -> pmf * 65536
// 4 px/thread. IN origin (y0-2, x0-4): [3][18][72].
// Per-(ic): inputs -> v[3][12] once; per-(ic,m): Wm[13] in registers.
// ---------------------------------------------------------------------------
__global__ __launch_bounds__(256) void final_kernel(
    const float* __restrict__ hbuf, const float* __restrict__ wf,
    const float* __restrict__ bf, float* __restrict__ out)
{
    const int g  = blockIdx.z;
    const int x0 = blockIdx.x * FTW, y0 = blockIdx.y * FTH;
    __shared__ __align__(16) float IN[3][FTH + 2][FTW + 8];
    const int tid = threadIdx.y * 16 + threadIdx.x;

    const float* wg = wf + (size_t)g * 9 * 3 * 25;  // [m][ic][25]
    const float* bg = bf + (size_t)g * 9;

    const float* base = hbuf + (size_t)g * 3 * HW;
    for (int i = tid; i < 3 * (FTH + 2) * ((FTW + 8) / 4); i += 256) { // 972
        int ch = i / 324, rem = i % 324, rr = rem / 18, q = rem % 18;
        int gy = y0 - 2 + rr, gx0 = x0 - 4 + 4 * q;
        float4 v = make_float4(0.f, 0.f, 0.f, 0.f);
        if (gy >= 0) {
            const float* rowp = base + (size_t)ch * HW + (size_t)gy * WW;
            if (gx0 >= 0 && gx0 + 3 < WW) {
                v = *(const float4*)(rowp + gx0);
            } else {
                float t[4];
#pragma unroll
                for (int p = 0; p < 4; ++p) {
                    int gx = gx0 + p;
                    t[p] = (gx >= 0 && gx < WW) ? rowp[gx] : 0.f;
                }
                v = make_float4(t[0], t[1], t[2], t[3]);
            }
        }
        *(float4*)&IN[ch][rr][4 * q] = v;
    }
    __syncthreads();

    const int xg = threadIdx.x, yy = threadIdx.y;
    float P[9][4];
#pragma unroll
    for (int m = 0; m < 9; ++m) {
        float b = bg[m];
#pragma unroll
        for (int p = 0; p < 4; ++p) P[m][p] = b;
    }

#pragma unroll
    for (int ic = 0; ic < 3; ++ic) {
        float v[3][12];
#pragma unroll
        for (int r = 0; r < 3; ++r) {
            const float* row = &IN[ic][yy + r][4 * xg];
            float4 u0 = *(const float4*)(row);
            float4 u1 = *(const float4*)(row + 4);
            float4 u2 = *(const float4*)(row + 8);
            v[r][0] = u0.x; v[r][1] = u0.y; v[r][2]  = u0.z; v[r][3]  = u0.w;
            v[r][4] = u1.x; v[r][5] = u1.y; v[r][6]  = u1.z; v[r][7]  = u1.w;
            v[r][8] = u2.x; v[r][9] = u2.y; v[r][10] = u2.z; v[r][11] = u2.w;
        }
#pragma unroll
        for (int m = 0; m < 9; ++m) {
            float Wm[13];
#pragma unroll
            for (int t = 0; t < 13; ++t)
                Wm[t] = wg[(m * 3 + ic) * 25 + t];
#pragma unroll
            for (int r = 0; r < 3; ++r) {
                const int cmax = (r < 2) ? 5 : 3;
#pragma unroll
                for (int c = 0; c < 5; ++c) {
                    if (c >= cmax) break;
                    float w = Wm[r * 5 + c];
#pragma unroll
                    for (int p = 0; p < 4; ++p)
                        P[m][p] += w * v[r][c + p + 2];   // IN origin x0-4
                }
            }
        }
    }

    // ---- mixture per pixel ----
    const float inv_sqrt2 = 0.70710678118654752440f;
    float wm0[4], wm1[4], wm2[4], mu0[4], mu1[4], mu2[4], k0[4], k1[4], k2[4];
#pragma unroll
    for (int p = 0; p < 4; ++p) {
        float lw0 = P[0][p], m0 = P[1][p], ls0 = P[2][p];
        float lw1 = P[3][p], m1 = P[4][p], ls1 = P[5][p];
        float lw2 = P[6][p], m2 = P[7][p], ls2 = P[8][p];
        float lmax = fmaxf(lw0, fmaxf(lw1, lw2));
        float e0 = __expf(lw0 - lmax), e1 = __expf(lw1 - lmax), e2 = __expf(lw2 - lmax);
        float inv_sum = fast_rcp(e0 + e1 + e2);
        wm0[p] = 0.5f * e0 * inv_sum;
        wm1[p] = 0.5f * e1 * inv_sum;
        wm2[p] = 0.5f * e2 * inv_sum;
        mu0[p] = m0; mu1[p] = m1; mu2[p] = m2;
        k0[p] = inv_sqrt2 * fast_rcp(fast_softplus(ls0) + 1e-6f);
        k1[p] = inv_sqrt2 * fast_rcp(fast_softplus(ls1) + 1e-6f);
        k2[p] = inv_sqrt2 * fast_rcp(fast_softplus(ls2) + 1e-6f);
    }

    const int gy = y0 + yy;
    float* ob = out + ((size_t)g * 8 * HH + gy) * WW + x0 + 4 * xg;
    float prev[4] = {0.f, 0.f, 0.f, 0.f};
#pragma unroll
    for (int j = 0; j <= 8; ++j) {
        float edge = (float)j - 4.0f;
        float cdf[4];
#pragma unroll
        for (int p = 0; p < 4; ++p) {
            cdf[p] = wm0[p] * (1.f + fast_erf((edge - mu0[p]) * k0[p]))
                   + wm1[p] * (1.f + fast_erf((edge - mu1[p]) * k1[p]))
                   + wm2[p] * (1.f + fast_erf((edge - mu2[p]) * k2[p]));
        }
        if (j > 0) {
            *(float4*)(ob + (size_t)(j - 1) * HW) =
                make_float4((cdf[0] - prev[0]) * 65536.f, (cdf[1] - prev[1]) * 65536.f,
                            (cdf[2] - prev[2]) * 65536.f, (cdf[3] - prev[3]) * 65536.f);
        }
#pragma unroll
        for (int p = 0; p < 4; ++p) prev[p] = cdf[p];
    }
}

// ---------------------------------------------------------------------------
extern "C" void kernel_launch(void* const* d_in, const int* in_sizes, int n_in,
                              void* d_out, int out_size, void* d_ws, size_t ws_size,
                              hipStream_t stream)
{
    const int*   data = (const int*)d_in[0];
    const float* w1   = (const float*)d_in[1];
    const float* b1   = (const float*)d_in[2];
    const float* rw   = (const float*)d_in[3];
    const float* rb   = (const float*)d_in[4];
    const float* wf   = (const float*)d_in[5];
    const float* bf   = (const float*)d_in[6];
    float* out = (float*)d_out;

    float* A = (float*)d_ws;
    float* B = A + (size_t)48 * HW;

    dim3 blk(16, 16, 1);
    dim3 grd(WW / FTW, HH / FTH, NG);

    conv1_kernel<<<grd, blk, 0, stream>>>(data, w1, b1, A);

    const float* cur = A;
    float* nxt = B;
    for (int i = 0; i < 5; ++i) {
        const float* wa = rw + (size_t)(i * 2 + 0) * 48 * 3 * 25;
        const float* ba = rb + (i * 2 + 0) * 48;
        const float* wb = rw + (size_t)(i * 2 + 1) * 48 * 3 * 25;
        const float* bb = rb + (i * 2 + 1) * 48;
        res_block_kernel<<<grd, blk, 0, stream>>>(cur, wa, ba, wb, bb, nxt);
        const float* t = cur; cur = nxt; nxt = (float*)t;
    }
    final_kernel<<<grd, blk, 0, stream>>>(cur, wf, bf, out);
}

// Round 7
// 319.191 us; speedup vs baseline: 1.1384x; 1.0464x over previous
//
#include <hip/hip_runtime.h>
#include <math.h>

#define HH 384
#define WW 384
#define NG 16
#define HW (HH*WW)

// fused tiles: 64 wide x 16 tall, 256 threads = (16 xg, 16 y), 4 px/thread
#define FTW 64
#define FTH 16

// ---------------------------------------------------------------------------
// Generic 13-tap (maskB) accumulate: a[oc][p] += W[oc][r*5+c] * row[c+p]
// P points at [row0][col0] of the input window; PITCH = row stride in floats.
// taps: r=0,1 -> c=0..4 ; r=2 -> c=0..2 (linear index r*5+c in 0..12)
// ---------------------------------------------------------------------------
template <int PITCH>
__device__ __forceinline__ void accum13(const float* __restrict__ P,
                                        int ty, int tx0,
                                        float (&a)[3][4],
                                        const float (&Wl)[3][13])
{
#pragma unroll
    for (int r = 0; r < 3; ++r) {
        const float* row = P + (ty + r) * PITCH + tx0;
        float4 u0 = *(const float4*)(row);
        float4 u1 = *(const float4*)(row + 4);
        float v[8] = {u0.x, u0.y, u0.z, u0.w, u1.x, u1.y, u1.z, u1.w};
        const int cmax = (r < 2) ? 5 : 3;
#pragma unroll
        for (int c = 0; c < 5; ++c) {
            if (c >= cmax) break;
#pragma unroll
            for (int oc = 0; oc < 3; ++oc) {
                float w = Wl[oc][r * 5 + c];
#pragma unroll
                for (int p = 0; p < 4; ++p)
                    a[oc][p] += w * v[c + p];
            }
        }
    }
}

// ---------------------------------------------------------------------------
// Layer 1: x = data - 3.5 ; h = relu(gconv(x, w1*maskA, b1))
// maskA taps: rows 0,1 all 5 cols; row 2 cols 0,1 (12 taps).
// ---------------------------------------------------------------------------
__global__ __launch_bounds__(256) void conv1_kernel(
    const int* __restrict__ data, const float* __restrict__ w1,
    const float* __restrict__ b1, float* __restrict__ h)
{
    const int g  = blockIdx.z;
    const int x0 = blockIdx.x * FTW, y0 = blockIdx.y * FTH;
    __shared__ __align__(16) float s_in[FTH + 2][FTW + 8];
    const int tid = threadIdx.y * 16 + threadIdx.x;

    const float* wg = w1 + (size_t)g * 3 * 25;
    const float* bg = b1 + (size_t)g * 3;

    // stage 18 rows x 72 cols (origin y0-2, x0-4), int -> float - 3.5
    const int* plane = data + g * HW;
    for (int i = tid; i < 18 * 18; i += 256) {
        int rr = i / 18, q = i % 18;
        int gy = y0 - 2 + rr, gx0 = x0 - 4 + 4 * q;
        float4 v = make_float4(0.f, 0.f, 0.f, 0.f);
        if (gy >= 0) {
            const int* rowp = plane + gy * WW;
            if (gx0 >= 0 && gx0 + 3 < WW) {
                int4 iv = *(const int4*)(rowp + gx0);
                v = make_float4((float)iv.x - 3.5f, (float)iv.y - 3.5f,
                                (float)iv.z - 3.5f, (float)iv.w - 3.5f);
            } else {
                float t[4];
#pragma unroll
                for (int p = 0; p < 4; ++p) {
                    int gx = gx0 + p;
                    t[p] = (gx >= 0 && gx < WW) ? (float)rowp[gx] - 3.5f : 0.f;
                }
                v = make_float4(t[0], t[1], t[2], t[3]);
            }
        }
        *(float4*)&s_in[rr][4 * q] = v;
    }
    __syncthreads();

    const int xg = threadIdx.x, yy = threadIdx.y;
    float a[3][4];
#pragma unroll
    for (int oc = 0; oc < 3; ++oc)
#pragma unroll
        for (int p = 0; p < 4; ++p) a[oc][p] = bg[oc];

#pragma unroll
    for (int r = 0; r < 3; ++r) {
        const float* row = &s_in[yy + r][4 * xg];
        float4 u0 = *(const float4*)(row);
        float4 u1 = *(const float4*)(row + 4);
        float4 u2 = *(const float4*)(row + 8);
        float v[12] = {u0.x, u0.y, u0.z, u0.w, u1.x, u1.y, u1.z, u1.w,
                       u2.x, u2.y, u2.z, u2.w};
        const int cmax = (r < 2) ? 5 : 2;      // maskA
#pragma unroll
        for (int c = 0; c < 5; ++c) {
            if (c >= cmax) break;
#pragma unroll
            for (int oc = 0; oc < 3; ++oc) {
                float w = wg[oc * 25 + r * 5 + c];
#pragma unroll
                for (int p = 0; p < 4; ++p)
                    a[oc][p] += w * v[c + p + 2];   // input origin x0-4
            }
        }
    }
    const int gy = y0 + yy;
    float* ob = h + (size_t)g * 3 * HW + (size_t)gy * WW + x0 + 4 * xg;
#pragma unroll
    for (int oc = 0; oc < 3; ++oc) {
        *(float4*)(ob + (size_t)oc * HW) =
            make_float4(fmaxf(a[oc][0], 0.f), fmaxf(a[oc][1], 0.f),
                        fmaxf(a[oc][2], 0.f), fmaxf(a[oc][3], 0.f));
    }
}

// ---------------------------------------------------------------------------
// Fused residual block: out = in + relu(convB(relu(convB(in, wa)), wb))
// IN origin (y0-4, x0-4): [3][20][72]; T origin (y0-2, x0-2): [3][18][68].
// conv-a items processed SEQUENTIALLY (unroll 1) to cap live registers.
// ---------------------------------------------------------------------------
__global__ __launch_bounds__(256) void res_block_kernel(
    const float* __restrict__ in, const float* __restrict__ wa,
    const float* __restrict__ ba, const float* __restrict__ wb,
    const float* __restrict__ bb, float* __restrict__ out)
{
    const int g  = blockIdx.z;
    const int x0 = blockIdx.x * FTW, y0 = blockIdx.y * FTH;
    __shared__ __align__(16) float IN[3][FTH + 4][FTW + 8];
    __shared__ __align__(16) float T [3][FTH + 2][FTW + 4];
    const int tid = threadIdx.y * 16 + threadIdx.x;

    const float* wga = wa + (size_t)g * 9 * 25;
    const float* bga = ba + (size_t)g * 3;
    const float* wgb = wb + (size_t)g * 9 * 25;
    const float* bgb = bb + (size_t)g * 3;

    // ---- stage input tile; interior blocks skip all bounds checks ----
    const float* base = in + (size_t)g * 3 * HW;
    const bool interior = (y0 >= 4) && (x0 >= 4) && (x0 + 68 <= WW);
    if (interior) {
        for (int i = tid; i < 1080; i += 256) {
            int ch = i / 360, rem = i % 360, rr = rem / 18, q = rem % 18;
            const float* rowp = base + (size_t)ch * HW
                              + (size_t)(y0 - 4 + rr) * WW + (x0 - 4 + 4 * q);
            *(float4*)&IN[ch][rr][4 * q] = *(const float4*)rowp;
        }
    } else {
        for (int i = tid; i < 1080; i += 256) {
            int ch = i / 360, rem = i % 360, rr = rem / 18, q = rem % 18;
            int gy = y0 - 4 + rr, gx0 = x0 - 4 + 4 * q;
            float4 v = make_float4(0.f, 0.f, 0.f, 0.f);
            if (gy >= 0) {
                const float* rowp = base + (size_t)ch * HW + (size_t)gy * WW;
                if (gx0 >= 0 && gx0 + 3 < WW) {
                    v = *(const float4*)(rowp + gx0);
                } else {
                    float t[4];
#pragma unroll
                    for (int p = 0; p < 4; ++p) {
                        int gx = gx0 + p;
                        t[p] = (gx >= 0 && gx < WW) ? rowp[gx] : 0.f;
                    }
                    v = make_float4(t[0], t[1], t[2], t[3]);
                }
            }
            *(float4*)&IN[ch][rr][4 * q] = v;
        }
    }
    __syncthreads();

    // ---- first conv: T = relu(convB(IN)) over 18x68 region (306 items) ----
#pragma unroll 1
    for (int it = 0; it < 2; ++it) {
        const int i = tid + (it << 8);
        if (i < 306) {
            const int ty = i / 17, tx0 = 4 * (i % 17);
            float a[3][4];
#pragma unroll
            for (int oc = 0; oc < 3; ++oc)
#pragma unroll
                for (int p = 0; p < 4; ++p) a[oc][p] = bga[oc];

#pragma unroll
            for (int ic = 0; ic < 3; ++ic) {
                float Wl[3][13];
#pragma unroll
                for (int oc = 0; oc < 3; ++oc)
#pragma unroll
                    for (int t = 0; t < 13; ++t)
                        Wl[oc][t] = wga[(oc * 3 + ic) * 25 + t];
                accum13<FTW + 8>(&IN[ic][0][0], ty, tx0, a, Wl);
            }

            const int gty = y0 - 2 + ty, gtx0 = x0 - 2 + tx0;
#pragma unroll
            for (int oc = 0; oc < 3; ++oc) {
                float r_[4];
#pragma unroll
                for (int p = 0; p < 4; ++p) {
                    int gx = gtx0 + p;
                    bool ok = (gty >= 0) && (gx >= 0) && (gx < WW);
                    r_[p] = ok ? fmaxf(a[oc][p], 0.f) : 0.f;
                }
                *(float4*)&T[oc][ty][tx0] = make_float4(r_[0], r_[1], r_[2], r_[3]);
            }
        }
    }
    __syncthreads();

    // ---- second conv + residual add + write ----
    const int xg = threadIdx.x, yy = threadIdx.y;
    float a[3][4];
#pragma unroll
    for (int oc = 0; oc < 3; ++oc)
#pragma unroll
        for (int p = 0; p < 4; ++p) a[oc][p] = bgb[oc];

#pragma unroll
    for (int ic = 0; ic < 3; ++ic) {
        float Wl[3][13];
#pragma unroll
        for (int oc = 0; oc < 3; ++oc)
#pragma unroll
            for (int t = 0; t < 13; ++t)
                Wl[oc][t] = wgb[(oc * 3 + ic) * 25 + t];
        accum13<FTW + 4>(&T[ic][0][0], yy, 4 * xg, a, Wl);
    }

    const int gy = y0 + yy;
    float* ob = out + (size_t)g * 3 * HW + (size_t)gy * WW + x0 + 4 * xg;
#pragma unroll
    for (int oc = 0; oc < 3; ++oc) {
        float4 h0 = *(const float4*)&IN[oc][yy + 4][4 * xg + 4];
        *(float4*)(ob + (size_t)oc * HW) =
            make_float4(h0.x + fmaxf(a[oc][0], 0.f), h0.y + fmaxf(a[oc][1], 0.f),
                        h0.z + fmaxf(a[oc][2], 0.f), h0.w + fmaxf(a[oc][3], 0.f));
    }
}

// ---------------------------------------------------------------------------
// Fast branchless transcendentals
// ---------------------------------------------------------------------------
__device__ __forceinline__ float fast_rcp(float x) {
    return __builtin_amdgcn_rcpf(x);
}

// softplus; sloppiness for very negative x harmless (enters via 1/(sp+1e-6)).
__device__ __forceinline__ float fast_softplus(float x) {
    float t = __expf(-fabsf(x));
    return fmaxf(x, 0.f) + __logf(1.f + t);
}

// ---------------------------------------------------------------------------
// Final conv (9 out ch per group) fused with mixture-CDF -> pmf * 65536.
// CDF via Bowling sigmoid approx: Phi(z) ~ 1/(1+exp(-(1.5976 z + 0.07056 z^3)))
// (max err ~1.4e-4 in CDF -> <~20 counts; threshold is 947 counts).
// ---------------------------------------------------------------------------
__global__ __launch_bounds__(256) void final_kernel(
    const float* __restrict__ hbuf, const float* __restrict__ wf,
    const float* __restrict__ bf, float* __restrict__ out)
{
    const int g  = blockIdx.z;
    const int x0 = blockIdx.x * FTW, y0 = blockIdx.y * FTH;
    __shared__ __align__(16) float IN[3][FTH + 2][FTW + 8];
    const int tid = threadIdx.y * 16 + threadIdx.x;

    const float* wg = wf + (size_t)g * 9 * 3 * 25;  // [m][ic][25]
    const float* bg = bf + (size_t)g * 9;

    const float* base = hbuf + (size_t)g * 3 * HW;
    const bool interior = (y0 >= 2) && (x0 >= 4) && (x0 + 68 <= WW);
    if (interior) {
        for (int i = tid; i < 972; i += 256) {
            int ch = i / 324, rem = i % 324, rr = rem / 18, q = rem % 18;
            const float* rowp = base + (size_t)ch * HW
                              + (size_t)(y0 - 2 + rr) * WW + (x0 - 4 + 4 * q);
            *(float4*)&IN[ch][rr][4 * q] = *(const float4*)rowp;
        }
    } else {
        for (int i = tid; i < 972; i += 256) {
            int ch = i / 324, rem = i % 324, rr = rem / 18, q = rem % 18;
            int gy = y0 - 2 + rr, gx0 = x0 - 4 + 4 * q;
            float4 v = make_float4(0.f, 0.f, 0.f, 0.f);
            if (gy >= 0) {
                const float* rowp = base + (size_t)ch * HW + (size_t)gy * WW;
                if (gx0 >= 0 && gx0 + 3 < WW) {
                    v = *(const float4*)(rowp + gx0);
                } else {
                    float t[4];
#pragma unroll
                    for (int p = 0; p < 4; ++p) {
                        int gx = gx0 + p;
                        t[p] = (gx >= 0 && gx < WW) ? rowp[gx] : 0.f;
                    }
                    v = make_float4(t[0], t[1], t[2], t[3]);
                }
            }
            *(float4*)&IN[ch][rr][4 * q] = v;
        }
    }
    __syncthreads();

    const int xg = threadIdx.x, yy = threadIdx.y;
    float P[9][4];
#pragma unroll
    for (int m = 0; m < 9; ++m) {
        float b = bg[m];
#pragma unroll
        for (int p = 0; p < 4; ++p) P[m][p] = b;
    }

#pragma unroll
    for (int ic = 0; ic < 3; ++ic) {
        float v[3][12];
#pragma unroll
        for (int r = 0; r < 3; ++r) {
            const float* row = &IN[ic][yy + r][4 * xg];
            float4 u0 = *(const float4*)(row);
            float4 u1 = *(const float4*)(row + 4);
            float4 u2 = *(const float4*)(row + 8);
            v[r][0] = u0.x; v[r][1] = u0.y; v[r][2]  = u0.z; v[r][3]  = u0.w;
            v[r][4] = u1.x; v[r][5] = u1.y; v[r][6]  = u1.z; v[r][7]  = u1.w;
            v[r][8] = u2.x; v[r][9] = u2.y; v[r][10] = u2.z; v[r][11] = u2.w;
        }
#pragma unroll
        for (int m = 0; m < 9; ++m) {
#pragma unroll
            for (int r = 0; r < 3; ++r) {
                const int cmax = (r < 2) ? 5 : 3;
#pragma unroll
                for (int c = 0; c < 5; ++c) {
                    if (c >= cmax) break;
                    float w = wg[(m * 3 + ic) * 25 + r * 5 + c];
#pragma unroll
                    for (int p = 0; p < 4; ++p)
                        P[m][p] += w * v[r][c + p + 2];   // IN origin x0-4
                }
            }
        }
    }

    // ---- mixture per pixel (sigmoid-CDF) ----
    float wm0[4], wm1[4], wm2[4], ks0[4], ks1[4], ks2[4], nm0[4], nm1[4], nm2[4];
#pragma unroll
    for (int p = 0; p < 4; ++p) {
        float lw0 = P[0][p], m0 = P[1][p], ls0 = P[2][p];
        float lw1 = P[3][p], m1 = P[4][p], ls1 = P[5][p];
        float lw2 = P[6][p], m2 = P[7][p], ls2 = P[8][p];
        float lmax = fmaxf(lw0, fmaxf(lw1, lw2));
        float e0 = __expf(lw0 - lmax), e1 = __expf(lw1 - lmax), e2 = __expf(lw2 - lmax);
        float inv_sum = fast_rcp(e0 + e1 + e2);
        wm0[p] = e0 * inv_sum;
        wm1[p] = e1 * inv_sum;
        wm2[p] = e2 * inv_sum;
        ks0[p] = fast_rcp(fast_softplus(ls0) + 1e-6f);   // 1/scale
        ks1[p] = fast_rcp(fast_softplus(ls1) + 1e-6f);
        ks2[p] = fast_rcp(fast_softplus(ls2) + 1e-6f);
        nm0[p] = -m0 * ks0[p];
        nm1[p] = -m1 * ks1[p];
        nm2[p] = -m2 * ks2[p];
    }

    const int gy = y0 + yy;
    float* ob = out + ((size_t)g * 8 * HH + gy) * WW + x0 + 4 * xg;
    float prev[4] = {0.f, 0.f, 0.f, 0.f};
#pragma unroll
    for (int j = 0; j <= 8; ++j) {
        float edge = (float)j - 4.0f;
        float cdf[4];
#pragma unroll
        for (int p = 0; p < 4; ++p) {
            // Phi(z) = 1/(1+exp(z*(-1.5976 - 0.07056 z^2)))
            float z0 = fmaf(edge, ks0[p], nm0[p]);
            float z1 = fmaf(edge, ks1[p], nm1[p]);
            float z2 = fmaf(edge, ks2[p], nm2[p]);
            float y0_ = z0 * fmaf(z0 * z0, -0.07056f, -1.5976f);
            float y1_ = z1 * fmaf(z1 * z1, -0.07056f, -1.5976f);
            float y2_ = z2 * fmaf(z2 * z2, -0.07056f, -1.5976f);
            float c = wm0[p] * fast_rcp(1.f + __expf(y0_));
            c = fmaf(wm1[p], fast_rcp(1.f + __expf(y1_)), c);
            c = fmaf(wm2[p], fast_rcp(1.f + __expf(y2_)), c);
            cdf[p] = c;
        }
        if (j > 0) {
            *(float4*)(ob + (size_t)(j - 1) * HW) =
                make_float4((cdf[0] - prev[0]) * 65536.f, (cdf[1] - prev[1]) * 65536.f,
                            (cdf[2] - prev[2]) * 65536.f, (cdf[3] - prev[3]) * 65536.f);
        }
#pragma unroll
        for (int p = 0; p < 4; ++p) prev[p] = cdf[p];
    }
}

// ---------------------------------------------------------------------------
extern "C" void kernel_launch(void* const* d_in, const int* in_sizes, int n_in,
                              void* d_out, int out_size, void* d_ws, size_t ws_size,
                              hipStream_t stream)
{
    const int*   data = (const int*)d_in[0];
    const float* w1   = (const float*)d_in[1];
    const float* b1   = (const float*)d_in[2];
    const float* rw   = (const float*)d_in[3];
    const float* rb   = (const float*)d_in[4];
    const float* wf   = (const float*)d_in[5];
    const float* bf   = (const float*)d_in[6];
    float* out = (float*)d_out;

    float* A = (float*)d_ws;
    float* B = A + (size_t)48 * HW;

    dim3 blk(16, 16, 1);
    dim3 grd(WW / FTW, HH / FTH, NG);

    conv1_kernel<<<grd, blk, 0, stream>>>(data, w1, b1, A);

    const float* cur = A;
    float* nxt = B;
    for (int i = 0; i < 5; ++i) {
        const float* wa = rw + (size_t)(i * 2 + 0) * 48 * 3 * 25;
        const float* ba = rb + (i * 2 + 0) * 48;
        const float* wb = rw + (size_t)(i * 2 + 1) * 48 * 3 * 25;
        const float* bb = rb + (i * 2 + 1) * 48;
        res_block_kernel<<<grd, blk, 0, stream>>>(cur, wa, ba, wb, bb, nxt);
        const float* t = cur; cur = nxt; nxt = (float*)t;
    }
    final_kernel<<<grd, blk, 0, stream>>>(cur, wf, bf, out);
}